// Round 1
// baseline (80.090 us; speedup 1.0000x reference)
//
#include <hip/hip_runtime.h>

#define OUT_H 256
#define OUT_W 192
#define HWPIX (OUT_H * OUT_W)   // 49152
#define NPTS 25
#define BATCH 64

// ---------------- compile-time constants: Li = inv(L) ----------------

constexpr double cx_ln(double x) {
  // natural log for x in ~[0.2, 8]; reduce to [0.75,1.5), atanh series
  int e = 0;
  while (x >= 1.5) { x *= 0.5; ++e; }
  while (x < 0.75) { x *= 2.0; --e; }
  double t = (x - 1.0) / (x + 1.0);
  double t2 = t * t, s = 0.0, term = t;
  for (int k = 0; k < 20; ++k) { s += term / (double)(2 * k + 1); term *= t2; }
  return 2.0 * s + (double)e * 0.6931471805599453094172321214581766;
}

struct Consts { float li[28][25]; };

constexpr Consts make_consts() {
  Consts out{};
  double PX[25] = {}, PY[25] = {};
  for (int n = 0; n < 25; ++n) {
    PX[n] = -1.0 + 0.5 * (double)(n / 5);   // meshgrid: P_X[n]=ax[n/5]
    PY[n] = -1.0 + 0.5 * (double)(n % 5);   //           P_Y[n]=ax[n%5]
  }
  double M[28][56] = {};
  for (int i = 0; i < 28; ++i)
    for (int j = 0; j < 56; ++j) M[i][j] = 0.0;
  for (int i = 0; i < 25; ++i) {
    for (int j = 0; j < 25; ++j) {
      double dx = PX[i] - PX[j], dy = PY[i] - PY[j];
      double d2 = dx * dx + dy * dy;
      M[i][j] = (d2 == 0.0) ? 0.0 : d2 * cx_ln(d2);  // ref: d2==0 -> 1 -> 1*ln1 = 0
    }
    M[i][25] = 1.0; M[i][26] = PX[i]; M[i][27] = PY[i];
    M[25][i] = 1.0; M[26][i] = PX[i]; M[27][i] = PY[i];
  }
  for (int i = 0; i < 28; ++i) M[i][28 + i] = 1.0;
  // Gauss-Jordan with partial pivoting (diagonal of K is 0 -> pivoting required)
  for (int k = 0; k < 28; ++k) {
    int piv = k;
    double mx = M[k][k] < 0.0 ? -M[k][k] : M[k][k];
    for (int r = k + 1; r < 28; ++r) {
      double a = M[r][k] < 0.0 ? -M[r][k] : M[r][k];
      if (a > mx) { mx = a; piv = r; }
    }
    if (piv != k)
      for (int j = 0; j < 56; ++j) { double t = M[k][j]; M[k][j] = M[piv][j]; M[piv][j] = t; }
    double inv = 1.0 / M[k][k];
    for (int j = 0; j < 56; ++j) M[k][j] *= inv;
    for (int r = 0; r < 28; ++r) {
      if (r == k) continue;
      double f = M[r][k];
      if (f != 0.0)
        for (int j = 0; j < 56; ++j) M[r][j] -= f * M[k][j];
    }
  }
  for (int k = 0; k < 28; ++k)
    for (int m = 0; m < 25; ++m) out.li[k][m] = (float)M[k][28 + m];
  return out;
}

constexpr Consts CC = make_consts();

__device__ constexpr float PXf[25] = {
  -1.f,-1.f,-1.f,-1.f,-1.f, -0.5f,-0.5f,-0.5f,-0.5f,-0.5f,
   0.f, 0.f, 0.f, 0.f, 0.f,  0.5f, 0.5f, 0.5f, 0.5f, 0.5f,
   1.f, 1.f, 1.f, 1.f, 1.f };
__device__ constexpr float PYf[25] = {
  -1.f,-0.5f,0.f,0.5f,1.f, -1.f,-0.5f,0.f,0.5f,1.f,
  -1.f,-0.5f,0.f,0.5f,1.f, -1.f,-0.5f,0.f,0.5f,1.f,
  -1.f,-0.5f,0.f,0.5f,1.f };

// ---------------- kernel A: coefficients C[b][axis][k], 64*2*28 = 3584 floats ----------------

__global__ __launch_bounds__(256) void tps_prep(const float* __restrict__ theta,
                                                float* __restrict__ C) {
  int t = threadIdx.x;
  for (int o = t; o < 3584; o += 256) {     // 14 outputs per thread
    int b = o / 56, rem = o % 56;
    int axis = rem / 28, kk = rem % 28;
    const float* th = theta + b * 50 + axis * 25;
    float acc = 0.f;
#pragma unroll
    for (int m = 0; m < 25; ++m) {
      float pv = axis ? PYf[m] : PXf[m];
      acc += CC.li[kk][m] * (th[m] + pv);
    }
    C[o] = acc;
  }
}

// ---------------- kernel B: main evaluation ----------------
// lane = pixel (coalesced float2 stores), wave = batch group of 16.
// U[28] (25 RBF + affine [1,gx,gy]) lives in registers, batch-shared.
// C reads are wave-uniform -> scalar loads.

__global__ __launch_bounds__(256) void tps_main(const float* __restrict__ C,
                                                float2* __restrict__ out) {
  int lane = threadIdx.x & 63;
  int wg = __builtin_amdgcn_readfirstlane((int)(threadIdx.x >> 6)); // 0..3, wave-uniform
  int p = (blockIdx.x << 6) + lane;          // 64 pixels per block, never crosses a row
  int w = p % OUT_W;
  int h = p / OUT_W;
  // bit-identical to np.linspace(-1,1,n).astype(float32)
  float gx = (float)(-1.0 + (double)w * (2.0 / 191.0));
  float gy = (float)(-1.0 + (double)h * (2.0 / 255.0));
  if (w == OUT_W - 1) gx = 1.0f;
  if (h == OUT_H - 1) gy = 1.0f;

  float U[28];
#pragma unroll
  for (int n = 0; n < 25; ++n) {
    float dx = gx - PXf[n];
    float dy = gy - PYf[n];
    float d2 = dx * dx + dy * dy;
    float u = d2 * __logf(d2);
    U[n] = (d2 == 0.0f) ? 0.0f : u;          // NaN from 0*(-inf) discarded by select
  }
  U[25] = 1.0f; U[26] = gx; U[27] = gy;

  const float* Cw = C + wg * 16 * 56;
  for (int i = 0; i < 16; ++i) {
    const float* Cb = Cw + i * 56;           // uniform address -> s_load
    float px = 0.f, py = 0.f;
#pragma unroll
    for (int k = 0; k < 28; ++k) {
      px += U[k] * Cb[k];
      py += U[k] * Cb[28 + k];
    }
    int b = (wg << 4) + i;
    out[b * HWPIX + p] = make_float2(px, py);
  }
}

// ---------------- launch ----------------

extern "C" void kernel_launch(void* const* d_in, const int* in_sizes, int n_in,
                              void* d_out, int out_size, void* d_ws, size_t ws_size,
                              hipStream_t stream) {
  const float* theta = (const float*)d_in[0];
  float* C = (float*)d_ws;                   // 3584 floats = 14336 B scratch
  float2* out = (float2*)d_out;

  hipLaunchKernelGGL(tps_prep, dim3(1), dim3(256), 0, stream, theta, C);
  hipLaunchKernelGGL(tps_main, dim3(HWPIX / 64), dim3(256), 0, stream, C, out);
}

// Round 2
// 75.190 us; speedup vs baseline: 1.0652x; 1.0652x over previous
//
#include <hip/hip_runtime.h>

#define OUT_H 256
#define OUT_W 192
#define HWPIX (OUT_H * OUT_W)   // 49152
#define BATCH 64

// ---------------- compile-time constants: Li = inv(L), cp = Li·P ----------------

constexpr double cx_ln(double x) {
  // natural log for x in ~[0.2, 8]; reduce to [0.75,1.5), atanh series
  int e = 0;
  while (x >= 1.5) { x *= 0.5; ++e; }
  while (x < 0.75) { x *= 2.0; --e; }
  double t = (x - 1.0) / (x + 1.0);
  double t2 = t * t, s = 0.0, term = t;
  for (int k = 0; k < 20; ++k) { s += term / (double)(2 * k + 1); term *= t2; }
  return 2.0 * s + (double)e * 0.6931471805599453094172321214581766;
}

struct Consts {
  float li[28][25];   // rows 0..24: W coeffs, rows 25..27: affine A
  float cp[2][28];    // Li · P_axis  (axis 0 = X, 1 = Y)
};

constexpr Consts make_consts() {
  Consts out{};
  double PX[25] = {}, PY[25] = {};
  for (int n = 0; n < 25; ++n) {
    PX[n] = -1.0 + 0.5 * (double)(n / 5);
    PY[n] = -1.0 + 0.5 * (double)(n % 5);
  }
  double M[28][56] = {};
  for (int i = 0; i < 28; ++i)
    for (int j = 0; j < 56; ++j) M[i][j] = 0.0;
  for (int i = 0; i < 25; ++i) {
    for (int j = 0; j < 25; ++j) {
      double dx = PX[i] - PX[j], dy = PY[i] - PY[j];
      double d2 = dx * dx + dy * dy;
      M[i][j] = (d2 == 0.0) ? 0.0 : d2 * cx_ln(d2);
    }
    M[i][25] = 1.0; M[i][26] = PX[i]; M[i][27] = PY[i];
    M[25][i] = 1.0; M[26][i] = PX[i]; M[27][i] = PY[i];
  }
  for (int i = 0; i < 28; ++i) M[i][28 + i] = 1.0;
  // Gauss-Jordan with partial pivoting (K's diagonal is 0)
  for (int k = 0; k < 28; ++k) {
    int piv = k;
    double mx = M[k][k] < 0.0 ? -M[k][k] : M[k][k];
    for (int r = k + 1; r < 28; ++r) {
      double a = M[r][k] < 0.0 ? -M[r][k] : M[r][k];
      if (a > mx) { mx = a; piv = r; }
    }
    if (piv != k)
      for (int j = 0; j < 56; ++j) { double t = M[k][j]; M[k][j] = M[piv][j]; M[piv][j] = t; }
    double inv = 1.0 / M[k][k];
    for (int j = 0; j < 56; ++j) M[k][j] *= inv;
    for (int r = 0; r < 28; ++r) {
      if (r == k) continue;
      double f = M[r][k];
      if (f != 0.0)
        for (int j = 0; j < 56; ++j) M[r][j] -= f * M[k][j];
    }
  }
  for (int k = 0; k < 28; ++k)
    for (int m = 0; m < 25; ++m) out.li[k][m] = (float)M[k][28 + m];
  for (int axis = 0; axis < 2; ++axis)
    for (int k = 0; k < 28; ++k) {
      double s = 0.0;
      for (int m = 0; m < 25; ++m)
        s += (double)out.li[k][m] * (axis ? PY[m] : PX[m]);
      out.cp[axis][k] = (float)s;
    }
  return out;
}

constexpr Consts CC = make_consts();

__device__ constexpr float PXf[25] = {
  -1.f,-1.f,-1.f,-1.f,-1.f, -0.5f,-0.5f,-0.5f,-0.5f,-0.5f,
   0.f, 0.f, 0.f, 0.f, 0.f,  0.5f, 0.5f, 0.5f, 0.5f, 0.5f,
   1.f, 1.f, 1.f, 1.f, 1.f };
__device__ constexpr float PYf[25] = {
  -1.f,-0.5f,0.f,0.5f,1.f, -1.f,-0.5f,0.f,0.5f,1.f,
  -1.f,-0.5f,0.f,0.5f,1.f, -1.f,-0.5f,0.f,0.5f,1.f,
  -1.f,-0.5f,0.f,0.5f,1.f };

// ---------------- fused kernel ----------------
// Block = 64 pixels x 64 batches. 768 blocks (3 per CU).
// Phase 1: stage theta (12.8 KB) into LDS, coalesced float4.
// Phase 2: 256 threads compute all 3584 coeffs; thread owns fixed (b,axis),
//          theta row in registers, Li rows wave-uniform (scalar K$ loads).
//          LDS layout C[b][k][axis] so phase-3 reads are float4.
// Phase 3: lane = pixel; wave = 16-batch group. U[28] in registers, reused
//          across all 16 batches. C reads are wave-uniform ds_read_b128
//          (broadcast => conflict-free). Stores: coalesced float2.

__global__ __launch_bounds__(256) void tps_fused(const float* __restrict__ theta,
                                                 float2* __restrict__ out) {
  __shared__ float sth[BATCH * 50];    // 3200 floats
  __shared__ float sC[BATCH * 56];     // 3584 floats, [b][k][axis] interleaved
  const int t = threadIdx.x;

  // ---- phase 1: stage theta ----
  {
    const float4* g4 = (const float4*)theta;
    float4* s4 = (float4*)sth;
#pragma unroll
    for (int i = 0; i < 4; ++i) {
      int idx = t + i * 256;
      if (idx < 800) s4[idx] = g4[idx];
    }
  }
  __syncthreads();

  // ---- phase 2: coefficients ----
  {
    const int pair = t & 127;
    const int b = pair >> 1, axis = pair & 1;
    const int kg = t >> 7;              // wave-uniform (waves 0,1 -> 0; 2,3 -> 1)
    float th[25];
    const float* src = sth + b * 50 + axis * 25;
#pragma unroll
    for (int m = 0; m < 25; ++m) th[m] = src[m];
#pragma unroll
    for (int j = 0; j < 14; ++j) {
      const int k = kg * 14 + j;        // wave-uniform -> Li row via s_load
      float acc = CC.cp[axis][k];
#pragma unroll
      for (int m = 0; m < 25; ++m) acc += CC.li[k][m] * th[m];
      sC[b * 56 + k * 2 + axis] = acc;
    }
  }
  __syncthreads();

  // ---- phase 3: evaluate ----
  const int lane = t & 63;
  const int wg = t >> 6;                // wave-uniform batch group 0..3
  const int p = (blockIdx.x << 6) + lane;   // 64 px/block, never crosses a row
  const int w = p % OUT_W;
  const int h = p / OUT_W;
  // bit-identical to np.linspace(-1,1,n).astype(float32)
  float gx = (float)(-1.0 + (double)w * (2.0 / 191.0));
  float gy = (float)(-1.0 + (double)h * (2.0 / 255.0));
  if (w == OUT_W - 1) gx = 1.0f;
  if (h == OUT_H - 1) gy = 1.0f;

  float U[28];
#pragma unroll
  for (int n = 0; n < 25; ++n) {
    float dx = gx - PXf[n];
    float dy = gy - PYf[n];
    float d2 = dx * dx + dy * dy;
    float u = d2 * __logf(d2);
    U[n] = (d2 == 0.0f) ? 0.0f : u;     // select discards NaN from 0*(-inf)
  }
  U[25] = 1.0f; U[26] = gx; U[27] = gy;

  const float4* cb = (const float4*)sC + wg * 16 * 14;  // 14 float4 per batch
  float2* op = out + p;
#pragma unroll 4
  for (int i = 0; i < 16; ++i) {
    const float4* c4 = cb + i * 14;     // wave-uniform -> ds_read_b128 broadcast
    float px = 0.f, py = 0.f;
#pragma unroll
    for (int j = 0; j < 14; ++j) {
      float4 c = c4[j];                 // (Cx[2j],Cy[2j],Cx[2j+1],Cy[2j+1])
      px += U[2 * j]     * c.x;  py += U[2 * j]     * c.y;
      px += U[2 * j + 1] * c.z;  py += U[2 * j + 1] * c.w;
    }
    op[(wg * 16 + i) * HWPIX] = make_float2(px, py);
  }
}

// ---------------- launch ----------------

extern "C" void kernel_launch(void* const* d_in, const int* in_sizes, int n_in,
                              void* d_out, int out_size, void* d_ws, size_t ws_size,
                              hipStream_t stream) {
  const float* theta = (const float*)d_in[0];
  float2* out = (float2*)d_out;
  hipLaunchKernelGGL(tps_fused, dim3(HWPIX / 64), dim3(256), 0, stream, theta, out);
}